// Round 1
// baseline (844.058 us; speedup 1.0000x reference)
//
#include <hip/hip_runtime.h>

constexpr float EPS = 1e-5f;

// ---------------- CSR build ----------------

__global__ void hist_kernel(const int* __restrict__ dst, int* __restrict__ cnt, int E) {
    int e = blockIdx.x * blockDim.x + threadIdx.x;
    if (e < E) atomicAdd(&cnt[dst[e]], 1);
}

// per-chunk (512) exclusive scan, chunk sums out
__global__ void scan1_kernel(const int* __restrict__ cnt, int* __restrict__ chunkExcl,
                             int* __restrict__ bsums, int n) {
    __shared__ int tmp[512];
    int t = threadIdx.x;
    int i = blockIdx.x * 512 + t;
    int v = (i < n) ? cnt[i] : 0;
    tmp[t] = v;
    __syncthreads();
    for (int off = 1; off < 512; off <<= 1) {
        int x = tmp[t];
        if (t >= off) x += tmp[t - off];
        __syncthreads();
        tmp[t] = x;
        __syncthreads();
    }
    if (i < n) chunkExcl[i] = tmp[t] - v;   // exclusive within chunk
    if (t == 511) bsums[blockIdx.x] = tmp[511];
}

__global__ void scan2_kernel(const int* __restrict__ bsums, int* __restrict__ boffs, int nb) {
    __shared__ int tmp[256];
    int t = threadIdx.x;
    int v = (t < nb) ? bsums[t] : 0;
    tmp[t] = v;
    __syncthreads();
    for (int off = 1; off < 256; off <<= 1) {
        int x = tmp[t];
        if (t >= off) x += tmp[t - off];
        __syncthreads();
        tmp[t] = x;
        __syncthreads();
    }
    if (t < nb) boffs[t] = tmp[t] - v;
}

__global__ void scan3_kernel(int* __restrict__ rowptr, int* __restrict__ cursor,
                             const int* __restrict__ boffs, const int* __restrict__ cnt,
                             float* __restrict__ degInv, int n, int E) {
    int i = blockIdx.x * blockDim.x + threadIdx.x;
    if (i < n) {
        int r = rowptr[i] + boffs[i >> 9];
        rowptr[i] = r;
        cursor[i] = r;
        int d = cnt[i] > 1 ? cnt[i] : 1;
        degInv[i] = 1.0f / (float)d;
    }
    if (i == 0) rowptr[n] = E;
}

__global__ void fill_kernel(const int* __restrict__ src, const int* __restrict__ dst,
                            int* __restrict__ cursor, int* __restrict__ csr_src, int E) {
    int e = blockIdx.x * blockDim.x + threadIdx.x;
    if (e < E) {
        int p = atomicAdd(&cursor[dst[e]], 1);
        csr_src[p] = src[e];
    }
}

// ---------------- mean aggregation (gather over CSR) ----------------
// 32 lanes per node, each lane owns one float4 column of the 128-wide row.
__global__ void aggregate_kernel(const float* __restrict__ X, const int* __restrict__ rowptr,
                                 const int* __restrict__ csr_src, const float* __restrict__ degInv,
                                 float* __restrict__ agg, int n) {
    int idx = blockIdx.x * blockDim.x + threadIdx.x;
    int v = idx >> 5;
    int t = idx & 31;
    if (v >= n) return;
    int beg = rowptr[v], end = rowptr[v + 1];
    float4 s = make_float4(0.f, 0.f, 0.f, 0.f);
    const float4* X4 = reinterpret_cast<const float4*>(X);
    for (int e = beg; e < end; ++e) {
        int u = csr_src[e];
        float4 xv = X4[(size_t)u * 32 + t];
        s.x += xv.x; s.y += xv.y; s.z += xv.z; s.w += xv.w;
    }
    float di = degInv[v];
    s.x *= di; s.y *= di; s.z *= di; s.w *= di;
    reinterpret_cast<float4*>(agg)[(size_t)v * 32 + t] = s;
}

// ---------------- fused dual-GEMM + bias + BN + ReLU ----------------
// OUT[r,c] = epilogue( sum_k AGG[r,k]*Wl[k,c] + sum_k X[r,k]*Wr[k,c] + bl[c] )
// virtual K = 256: k<128 -> (AGG, Wl); k>=128 -> (X, Wr)
template <int DOUT, bool BNRELU>
__global__ __launch_bounds__(256) void fused_linear_kernel(
    const float* __restrict__ AGG, const float* __restrict__ X,
    const float* __restrict__ Wl, const float* __restrict__ bl,
    const float* __restrict__ Wr,
    const float* __restrict__ g, const float* __restrict__ bb,
    const float* __restrict__ mm, const float* __restrict__ vv,
    float* __restrict__ OUT, int n) {
    constexpr int TN = DOUT / 16;            // 8 for 128, 4 for 64
    __shared__ float As[8][128];
    __shared__ float Ws[8][DOUT];

    int tid = threadIdx.x;
    int row0 = blockIdx.x * 128;
    int tx = tid & 15;       // col group
    int ty = tid >> 4;       // row group

    float acc[8][TN];
#pragma unroll
    for (int i = 0; i < 8; ++i)
#pragma unroll
        for (int j = 0; j < TN; ++j) acc[i][j] = 0.f;

    int arow = tid >> 1;         // 0..127
    int apart = tid & 1;         // which half of the 8-k chunk

    for (int kt = 0; kt < 32; ++kt) {
        int kg = kt * 8;
        const float* Asrc = (kg < 128) ? AGG : X;
        int ka = (kg < 128) ? kg : (kg - 128);
        const float* Wsrc = (kg < 128) ? Wl : Wr;
        int kw = ka;

        // load A chunk: rows row0..row0+127, ks ka..ka+7
        float4 av = make_float4(0.f, 0.f, 0.f, 0.f);
        int r = row0 + arow;
        if (r < n)
            av = *reinterpret_cast<const float4*>(Asrc + (size_t)r * 128 + ka + apart * 4);

        // load W chunk: rows kw..kw+7, all DOUT cols
        float4 wv = make_float4(0.f, 0.f, 0.f, 0.f);
        int wr, wc;
        if (DOUT == 128) {
            wr = tid >> 5; wc = (tid & 31) * 4;
            wv = *reinterpret_cast<const float4*>(Wsrc + (size_t)(kw + wr) * DOUT + wc);
        } else {
            wr = tid >> 4; wc = (tid & 15) * 4;
            if (tid < 128)
                wv = *reinterpret_cast<const float4*>(Wsrc + (size_t)(kw + wr) * DOUT + wc);
        }

        __syncthreads();   // previous iteration's reads done before overwrite
        As[apart * 4 + 0][arow] = av.x;
        As[apart * 4 + 1][arow] = av.y;
        As[apart * 4 + 2][arow] = av.z;
        As[apart * 4 + 3][arow] = av.w;
        if (DOUT == 128 || tid < 128) {
            Ws[wr][wc + 0] = wv.x;
            Ws[wr][wc + 1] = wv.y;
            Ws[wr][wc + 2] = wv.z;
            Ws[wr][wc + 3] = wv.w;
        }
        __syncthreads();

#pragma unroll
        for (int kk = 0; kk < 8; ++kk) {
            float a[8], w[TN];
#pragma unroll
            for (int i = 0; i < 8; ++i) a[i] = As[kk][ty * 8 + i];
#pragma unroll
            for (int j = 0; j < TN; ++j) w[j] = Ws[kk][tx * TN + j];
#pragma unroll
            for (int i = 0; i < 8; ++i)
#pragma unroll
                for (int j = 0; j < TN; ++j) acc[i][j] += a[i] * w[j];
        }
    }

    // epilogue
#pragma unroll
    for (int i = 0; i < 8; ++i) {
        int r = row0 + ty * 8 + i;
        if (r >= n) continue;
#pragma unroll
        for (int j = 0; j < TN; ++j) {
            int c = tx * TN + j;
            float h = acc[i][j] + bl[c];
            if (BNRELU) {
                h = g[c] * (h - mm[c]) * rsqrtf(vv[c] + EPS) + bb[c];
                h = fmaxf(h, 0.f);
            }
            OUT[(size_t)r * DOUT + c] = h;
        }
    }
}

// ---------------- log_softmax over 64 cols, wave per node, in place ----------------
__global__ void logsoftmax_kernel(float* __restrict__ h, int n) {
    int v = blockIdx.x * 4 + (threadIdx.x >> 6);
    int lane = threadIdx.x & 63;
    if (v >= n) return;
    float x = h[(size_t)v * 64 + lane];
    float mx = x;
    for (int o = 32; o; o >>= 1) mx = fmaxf(mx, __shfl_xor(mx, o));
    float e = __expf(x - mx);
    float s = e;
    for (int o = 32; o; o >>= 1) s += __shfl_xor(s, o);
    h[(size_t)v * 64 + lane] = x - mx - __logf(s);
}

// ---------------- launch ----------------

extern "C" void kernel_launch(void* const* d_in, const int* in_sizes, int n_in,
                              void* d_out, int out_size, void* d_ws, size_t ws_size,
                              hipStream_t stream) {
    const float* x   = (const float*)d_in[0];
    const int*   ei  = (const int*)d_in[1];
    const float* Wl0 = (const float*)d_in[2];
    const float* bl0 = (const float*)d_in[3];
    const float* Wr0 = (const float*)d_in[4];
    const float* g0  = (const float*)d_in[5];
    const float* b0  = (const float*)d_in[6];
    const float* m0  = (const float*)d_in[7];
    const float* v0  = (const float*)d_in[8];
    const float* Wl1 = (const float*)d_in[9];
    const float* bl1 = (const float*)d_in[10];
    const float* Wr1 = (const float*)d_in[11];
    const float* g1  = (const float*)d_in[12];
    const float* b1  = (const float*)d_in[13];
    const float* m1  = (const float*)d_in[14];
    const float* v1  = (const float*)d_in[15];
    const float* Wl2 = (const float*)d_in[16];
    const float* bl2 = (const float*)d_in[17];
    const float* Wr2 = (const float*)d_in[18];
    float* out = (float*)d_out;

    const int N = in_sizes[0] / 128;
    const int E = in_sizes[1] / 2;
    const int* src = ei;
    const int* dst = ei + E;

    char* ws = (char*)d_ws;
    size_t off = 0;
    auto alloc = [&](size_t bytes) -> void* {
        void* p = ws + off;
        off += (bytes + 255) & ~(size_t)255;
        return p;
    };
    int*   cnt    = (int*)alloc((size_t)N * 4);
    int*   rowptr = (int*)alloc((size_t)(N + 1) * 4);
    int*   cursor = (int*)alloc((size_t)N * 4);
    int*   bsums  = (int*)alloc(1024);
    int*   boffs  = (int*)alloc(1024);
    float* degInv = (float*)alloc((size_t)N * 4);
    int*   csr    = (int*)alloc((size_t)E * 4);
    float* agg    = (float*)alloc((size_t)N * 128 * 4);
    float* hA     = (float*)alloc((size_t)N * 128 * 4);
    float* hB     = (float*)alloc((size_t)N * 128 * 4);

    hipMemsetAsync(cnt, 0, (size_t)N * 4, stream);

    hist_kernel<<<(E + 255) / 256, 256, 0, stream>>>(dst, cnt, E);
    int nb = (N + 511) / 512;
    scan1_kernel<<<nb, 512, 0, stream>>>(cnt, rowptr, bsums, N);
    scan2_kernel<<<1, 256, 0, stream>>>(bsums, boffs, nb);
    scan3_kernel<<<(N + 255) / 256, 256, 0, stream>>>(rowptr, cursor, boffs, cnt, degInv, N, E);
    fill_kernel<<<(E + 255) / 256, 256, 0, stream>>>(src, dst, cursor, csr, E);

    int aggGrid = ((size_t)N * 32 + 255) / 256;
    int gemmGrid = (N + 127) / 128;

    // layer 0
    aggregate_kernel<<<aggGrid, 256, 0, stream>>>(x, rowptr, csr, degInv, agg, N);
    fused_linear_kernel<128, true><<<gemmGrid, 256, 0, stream>>>(
        agg, x, Wl0, bl0, Wr0, g0, b0, m0, v0, hA, N);
    // layer 1
    aggregate_kernel<<<aggGrid, 256, 0, stream>>>(hA, rowptr, csr, degInv, agg, N);
    fused_linear_kernel<128, true><<<gemmGrid, 256, 0, stream>>>(
        agg, hA, Wl1, bl1, Wr1, g1, b1, m1, v1, hB, N);
    // layer 2 -> d_out
    aggregate_kernel<<<aggGrid, 256, 0, stream>>>(hB, rowptr, csr, degInv, agg, N);
    fused_linear_kernel<64, false><<<gemmGrid, 256, 0, stream>>>(
        agg, hB, Wl2, bl2, Wr2, nullptr, nullptr, nullptr, nullptr, out, N);

    logsoftmax_kernel<<<(N + 3) / 4, 256, 0, stream>>>(out, N);
}

// Round 2
// 751.316 us; speedup vs baseline: 1.1234x; 1.1234x over previous
//
#include <hip/hip_runtime.h>

constexpr float EPS = 1e-5f;

// ---------------- CSR build ----------------

__global__ void hist_kernel(const int* __restrict__ dst, int* __restrict__ cnt, int E) {
    int e = blockIdx.x * blockDim.x + threadIdx.x;
    if (e < E) atomicAdd(&cnt[dst[e]], 1);
}

__global__ void scan1_kernel(const int* __restrict__ cnt, int* __restrict__ chunkExcl,
                             int* __restrict__ bsums, int n) {
    __shared__ int tmp[512];
    int t = threadIdx.x;
    int i = blockIdx.x * 512 + t;
    int v = (i < n) ? cnt[i] : 0;
    tmp[t] = v;
    __syncthreads();
    for (int off = 1; off < 512; off <<= 1) {
        int x = tmp[t];
        if (t >= off) x += tmp[t - off];
        __syncthreads();
        tmp[t] = x;
        __syncthreads();
    }
    if (i < n) chunkExcl[i] = tmp[t] - v;
    if (t == 511) bsums[blockIdx.x] = tmp[511];
}

__global__ void scan2_kernel(const int* __restrict__ bsums, int* __restrict__ boffs, int nb) {
    __shared__ int tmp[256];
    int t = threadIdx.x;
    int v = (t < nb) ? bsums[t] : 0;
    tmp[t] = v;
    __syncthreads();
    for (int off = 1; off < 256; off <<= 1) {
        int x = tmp[t];
        if (t >= off) x += tmp[t - off];
        __syncthreads();
        tmp[t] = x;
        __syncthreads();
    }
    if (t < nb) boffs[t] = tmp[t] - v;
}

__global__ void scan3_kernel(int* __restrict__ rowptr, int* __restrict__ cursor,
                             const int* __restrict__ boffs, const int* __restrict__ cnt,
                             float* __restrict__ degInv, int n, int E) {
    int i = blockIdx.x * blockDim.x + threadIdx.x;
    if (i < n) {
        int r = rowptr[i] + boffs[i >> 9];
        rowptr[i] = r;
        cursor[i] = r;
        int d = cnt[i] > 1 ? cnt[i] : 1;
        degInv[i] = 1.0f / (float)d;
    }
    if (i == 0) rowptr[n] = E;
}

__global__ void fill_kernel(const int* __restrict__ src, const int* __restrict__ dst,
                            int* __restrict__ cursor, int* __restrict__ csr_src, int E) {
    int e = blockIdx.x * blockDim.x + threadIdx.x;
    if (e < E) {
        int p = atomicAdd(&cursor[dst[e]], 1);
        csr_src[p] = src[e];
    }
}

// ---------------- mean aggregation over 128-wide rows ----------------
// 32 lanes per node, each lane owns one float4 column. Edge loop unrolled x4
// so each lane group keeps 4 independent gathers in flight.
__global__ void aggregate_kernel(const float* __restrict__ X, const int* __restrict__ rowptr,
                                 const int* __restrict__ csr_src, const float* __restrict__ degInv,
                                 float* __restrict__ agg, int n) {
    int idx = blockIdx.x * blockDim.x + threadIdx.x;
    int v = idx >> 5;
    int t = idx & 31;
    if (v >= n) return;
    int beg = rowptr[v], end = rowptr[v + 1];
    const float4* X4 = reinterpret_cast<const float4*>(X);
    float4 s0 = make_float4(0.f, 0.f, 0.f, 0.f);
    float4 s1 = make_float4(0.f, 0.f, 0.f, 0.f);
    int e = beg;
    for (; e + 4 <= end; e += 4) {
        int u0 = csr_src[e + 0];
        int u1 = csr_src[e + 1];
        int u2 = csr_src[e + 2];
        int u3 = csr_src[e + 3];
        float4 a = X4[(size_t)u0 * 32 + t];
        float4 b = X4[(size_t)u1 * 32 + t];
        float4 c = X4[(size_t)u2 * 32 + t];
        float4 d = X4[(size_t)u3 * 32 + t];
        s0.x += a.x + b.x; s0.y += a.y + b.y; s0.z += a.z + b.z; s0.w += a.w + b.w;
        s1.x += c.x + d.x; s1.y += c.y + d.y; s1.z += c.z + d.z; s1.w += c.w + d.w;
    }
    for (; e < end; ++e) {
        int u = csr_src[e];
        float4 a = X4[(size_t)u * 32 + t];
        s0.x += a.x; s0.y += a.y; s0.z += a.z; s0.w += a.w;
    }
    float di = degInv[v];
    float4 s;
    s.x = (s0.x + s1.x) * di;
    s.y = (s0.y + s1.y) * di;
    s.z = (s0.z + s1.z) * di;
    s.w = (s0.w + s1.w) * di;
    reinterpret_cast<float4*>(agg)[(size_t)v * 32 + t] = s;
}

// ---------------- fused dual-GEMM + bias + BN + ReLU (layers 0,1) ----------------
template <int DOUT, bool BNRELU>
__global__ __launch_bounds__(256) void fused_linear_kernel(
    const float* __restrict__ AGG, const float* __restrict__ X,
    const float* __restrict__ Wl, const float* __restrict__ bl,
    const float* __restrict__ Wr,
    const float* __restrict__ g, const float* __restrict__ bb,
    const float* __restrict__ mm, const float* __restrict__ vv,
    float* __restrict__ OUT, int n) {
    constexpr int TN = DOUT / 16;
    __shared__ float As[8][128];
    __shared__ float Ws[8][DOUT];

    int tid = threadIdx.x;
    int row0 = blockIdx.x * 128;
    int tx = tid & 15;
    int ty = tid >> 4;

    float acc[8][TN];
#pragma unroll
    for (int i = 0; i < 8; ++i)
#pragma unroll
        for (int j = 0; j < TN; ++j) acc[i][j] = 0.f;

    int arow = tid >> 1;
    int apart = tid & 1;

    for (int kt = 0; kt < 32; ++kt) {
        int kg = kt * 8;
        const float* Asrc = (kg < 128) ? AGG : X;
        int ka = (kg < 128) ? kg : (kg - 128);
        const float* Wsrc = (kg < 128) ? Wl : Wr;
        int kw = ka;

        float4 av = make_float4(0.f, 0.f, 0.f, 0.f);
        int r = row0 + arow;
        if (r < n)
            av = *reinterpret_cast<const float4*>(Asrc + (size_t)r * 128 + ka + apart * 4);

        float4 wv = make_float4(0.f, 0.f, 0.f, 0.f);
        int wr, wc;
        if (DOUT == 128) {
            wr = tid >> 5; wc = (tid & 31) * 4;
            wv = *reinterpret_cast<const float4*>(Wsrc + (size_t)(kw + wr) * DOUT + wc);
        } else {
            wr = tid >> 4; wc = (tid & 15) * 4;
            if (tid < 128)
                wv = *reinterpret_cast<const float4*>(Wsrc + (size_t)(kw + wr) * DOUT + wc);
        }

        __syncthreads();
        As[apart * 4 + 0][arow] = av.x;
        As[apart * 4 + 1][arow] = av.y;
        As[apart * 4 + 2][arow] = av.z;
        As[apart * 4 + 3][arow] = av.w;
        if (DOUT == 128 || tid < 128) {
            Ws[wr][wc + 0] = wv.x;
            Ws[wr][wc + 1] = wv.y;
            Ws[wr][wc + 2] = wv.z;
            Ws[wr][wc + 3] = wv.w;
        }
        __syncthreads();

#pragma unroll
        for (int kk = 0; kk < 8; ++kk) {
            float a[8], w[TN];
#pragma unroll
            for (int i = 0; i < 8; ++i) a[i] = As[kk][ty * 8 + i];
#pragma unroll
            for (int j = 0; j < TN; ++j) w[j] = Ws[kk][tx * TN + j];
#pragma unroll
            for (int i = 0; i < 8; ++i)
#pragma unroll
                for (int j = 0; j < TN; ++j) acc[i][j] += a[i] * w[j];
        }
    }

#pragma unroll
    for (int i = 0; i < 8; ++i) {
        int r = row0 + ty * 8 + i;
        if (r >= n) continue;
#pragma unroll
        for (int j = 0; j < TN; ++j) {
            int c = tx * TN + j;
            float h = acc[i][j] + bl[c];
            if (BNRELU) {
                h = g[c] * (h - mm[c]) * rsqrtf(vv[c] + EPS) + bb[c];
                h = fmaxf(h, 0.f);
            }
            OUT[(size_t)r * DOUT + c] = h;
        }
    }
}

// ---------------- layer 2: dual linear producing tmpL = H@Wl, tmpR = H@Wr + bl ----------------
__global__ __launch_bounds__(256) void dual_linear64_kernel(
    const float* __restrict__ H,
    const float* __restrict__ Wl, const float* __restrict__ bl,
    const float* __restrict__ Wr,
    float* __restrict__ tmpL, float* __restrict__ tmpR, int n) {
    __shared__ float As[8][128];
    __shared__ float WsL[8][64];
    __shared__ float WsR[8][64];

    int tid = threadIdx.x;
    int row0 = blockIdx.x * 128;
    int tx = tid & 15;   // 4 cols each -> 64
    int ty = tid >> 4;   // 8 rows each -> 128

    float accL[8][4], accR[8][4];
#pragma unroll
    for (int i = 0; i < 8; ++i)
#pragma unroll
        for (int j = 0; j < 4; ++j) { accL[i][j] = 0.f; accR[i][j] = 0.f; }

    int arow = tid >> 1;
    int apart = tid & 1;
    int wr = tid >> 5;          // 0..7
    int wc = (tid & 31) * 2;    // 0..62

    for (int kt = 0; kt < 16; ++kt) {
        int kg = kt * 8;

        float4 av = make_float4(0.f, 0.f, 0.f, 0.f);
        int r = row0 + arow;
        if (r < n)
            av = *reinterpret_cast<const float4*>(H + (size_t)r * 128 + kg + apart * 4);

        float2 wlv = *reinterpret_cast<const float2*>(Wl + (size_t)(kg + wr) * 64 + wc);
        float2 wrv = *reinterpret_cast<const float2*>(Wr + (size_t)(kg + wr) * 64 + wc);

        __syncthreads();
        As[apart * 4 + 0][arow] = av.x;
        As[apart * 4 + 1][arow] = av.y;
        As[apart * 4 + 2][arow] = av.z;
        As[apart * 4 + 3][arow] = av.w;
        WsL[wr][wc + 0] = wlv.x;
        WsL[wr][wc + 1] = wlv.y;
        WsR[wr][wc + 0] = wrv.x;
        WsR[wr][wc + 1] = wrv.y;
        __syncthreads();

#pragma unroll
        for (int kk = 0; kk < 8; ++kk) {
            float a[8], wl[4], wrg[4];
#pragma unroll
            for (int i = 0; i < 8; ++i) a[i] = As[kk][ty * 8 + i];
#pragma unroll
            for (int j = 0; j < 4; ++j) {
                wl[j]  = WsL[kk][tx * 4 + j];
                wrg[j] = WsR[kk][tx * 4 + j];
            }
#pragma unroll
            for (int i = 0; i < 8; ++i)
#pragma unroll
                for (int j = 0; j < 4; ++j) {
                    accL[i][j] += a[i] * wl[j];
                    accR[i][j] += a[i] * wrg[j];
                }
        }
    }

#pragma unroll
    for (int i = 0; i < 8; ++i) {
        int r = row0 + ty * 8 + i;
        if (r >= n) continue;
#pragma unroll
        for (int j = 0; j < 4; ++j) {
            int c = tx * 4 + j;
            tmpL[(size_t)r * 64 + c] = accL[i][j];
            tmpR[(size_t)r * 64 + c] = accR[i][j] + bl[c];
        }
    }
}

// ---------------- final: out = log_softmax( mean-agg(tmpL) + tmpR ) ----------------
// 16 lanes per node, each lane owns one float4 column of the 64-wide row.
__global__ void agg64_lsm_kernel(const float* __restrict__ tmpL, const float* __restrict__ tmpR,
                                 const int* __restrict__ rowptr, const int* __restrict__ csr_src,
                                 const float* __restrict__ degInv,
                                 float* __restrict__ out, int n) {
    int idx = blockIdx.x * blockDim.x + threadIdx.x;
    int v = idx >> 4;
    int t = idx & 15;
    if (v >= n) return;
    int beg = rowptr[v], end = rowptr[v + 1];
    const float4* L4 = reinterpret_cast<const float4*>(tmpL);
    float4 s0 = make_float4(0.f, 0.f, 0.f, 0.f);
    float4 s1 = make_float4(0.f, 0.f, 0.f, 0.f);
    int e = beg;
    for (; e + 4 <= end; e += 4) {
        int u0 = csr_src[e + 0];
        int u1 = csr_src[e + 1];
        int u2 = csr_src[e + 2];
        int u3 = csr_src[e + 3];
        float4 a = L4[(size_t)u0 * 16 + t];
        float4 b = L4[(size_t)u1 * 16 + t];
        float4 c = L4[(size_t)u2 * 16 + t];
        float4 d = L4[(size_t)u3 * 16 + t];
        s0.x += a.x + b.x; s0.y += a.y + b.y; s0.z += a.z + b.z; s0.w += a.w + b.w;
        s1.x += c.x + d.x; s1.y += c.y + d.y; s1.z += c.z + d.z; s1.w += c.w + d.w;
    }
    for (; e < end; ++e) {
        int u = csr_src[e];
        float4 a = L4[(size_t)u * 16 + t];
        s0.x += a.x; s0.y += a.y; s0.z += a.z; s0.w += a.w;
    }
    float di = degInv[v];
    float4 r4 = reinterpret_cast<const float4*>(tmpR)[(size_t)v * 16 + t];
    float y0 = (s0.x + s1.x) * di + r4.x;
    float y1 = (s0.y + s1.y) * di + r4.y;
    float y2 = (s0.z + s1.z) * di + r4.z;
    float y3 = (s0.w + s1.w) * di + r4.w;

    float mx = fmaxf(fmaxf(y0, y1), fmaxf(y2, y3));
#pragma unroll
    for (int o = 1; o < 16; o <<= 1) mx = fmaxf(mx, __shfl_xor(mx, o));
    float s = __expf(y0 - mx) + __expf(y1 - mx) + __expf(y2 - mx) + __expf(y3 - mx);
#pragma unroll
    for (int o = 1; o < 16; o <<= 1) s += __shfl_xor(s, o);
    float lse = mx + __logf(s);

    float4 o4;
    o4.x = y0 - lse; o4.y = y1 - lse; o4.z = y2 - lse; o4.w = y3 - lse;
    reinterpret_cast<float4*>(out)[(size_t)v * 16 + t] = o4;
}

// ---------------- launch ----------------

extern "C" void kernel_launch(void* const* d_in, const int* in_sizes, int n_in,
                              void* d_out, int out_size, void* d_ws, size_t ws_size,
                              hipStream_t stream) {
    const float* x   = (const float*)d_in[0];
    const int*   ei  = (const int*)d_in[1];
    const float* Wl0 = (const float*)d_in[2];
    const float* bl0 = (const float*)d_in[3];
    const float* Wr0 = (const float*)d_in[4];
    const float* g0  = (const float*)d_in[5];
    const float* b0  = (const float*)d_in[6];
    const float* m0  = (const float*)d_in[7];
    const float* v0  = (const float*)d_in[8];
    const float* Wl1 = (const float*)d_in[9];
    const float* bl1 = (const float*)d_in[10];
    const float* Wr1 = (const float*)d_in[11];
    const float* g1  = (const float*)d_in[12];
    const float* b1  = (const float*)d_in[13];
    const float* m1  = (const float*)d_in[14];
    const float* v1  = (const float*)d_in[15];
    const float* Wl2 = (const float*)d_in[16];
    const float* bl2 = (const float*)d_in[17];
    const float* Wr2 = (const float*)d_in[18];
    float* out = (float*)d_out;

    const int N = in_sizes[0] / 128;
    const int E = in_sizes[1] / 2;
    const int* src = ei;
    const int* dst = ei + E;

    char* ws = (char*)d_ws;
    size_t off = 0;
    auto alloc = [&](size_t bytes) -> void* {
        void* p = ws + off;
        off += (bytes + 255) & ~(size_t)255;
        return p;
    };
    int*   cnt    = (int*)alloc((size_t)N * 4);
    int*   rowptr = (int*)alloc((size_t)(N + 1) * 4);
    int*   cursor = (int*)alloc((size_t)N * 4);
    int*   bsums  = (int*)alloc(1024);
    int*   boffs  = (int*)alloc(1024);
    float* degInv = (float*)alloc((size_t)N * 4);
    int*   csr    = (int*)alloc((size_t)E * 4);
    float* agg    = (float*)alloc((size_t)N * 128 * 4);
    float* hA     = (float*)alloc((size_t)N * 128 * 4);
    float* hB     = (float*)alloc((size_t)N * 128 * 4);
    float* tmpL   = (float*)alloc((size_t)N * 64 * 4);
    float* tmpR   = (float*)alloc((size_t)N * 64 * 4);

    hipMemsetAsync(cnt, 0, (size_t)N * 4, stream);

    hist_kernel<<<(E + 255) / 256, 256, 0, stream>>>(dst, cnt, E);
    int nb = (N + 511) / 512;
    scan1_kernel<<<nb, 512, 0, stream>>>(cnt, rowptr, bsums, N);
    scan2_kernel<<<1, 256, 0, stream>>>(bsums, boffs, nb);
    scan3_kernel<<<(N + 255) / 256, 256, 0, stream>>>(rowptr, cursor, boffs, cnt, degInv, N, E);
    fill_kernel<<<(E + 255) / 256, 256, 0, stream>>>(src, dst, cursor, csr, E);

    int aggGrid = (int)(((size_t)N * 32 + 255) / 256);
    int gemmGrid = (N + 127) / 128;

    // layer 0
    aggregate_kernel<<<aggGrid, 256, 0, stream>>>(x, rowptr, csr, degInv, agg, N);
    fused_linear_kernel<128, true><<<gemmGrid, 256, 0, stream>>>(
        agg, x, Wl0, bl0, Wr0, g0, b0, m0, v0, hA, N);
    // layer 1
    aggregate_kernel<<<aggGrid, 256, 0, stream>>>(hA, rowptr, csr, degInv, agg, N);
    fused_linear_kernel<128, true><<<gemmGrid, 256, 0, stream>>>(
        agg, hA, Wl1, bl1, Wr1, g1, b1, m1, v1, hB, N);
    // layer 2: transform first (aggregation is linear), then 64-wide aggregate + fused log_softmax
    dual_linear64_kernel<<<gemmGrid, 256, 0, stream>>>(hB, Wl2, bl2, Wr2, tmpL, tmpR, N);
    agg64_lsm_kernel<<<(int)(((size_t)N * 16 + 255) / 256), 256, 0, stream>>>(
        tmpL, tmpR, rowptr, csr, degInv, out, N);
}

// Round 3
// 631.561 us; speedup vs baseline: 1.3365x; 1.1896x over previous
//
#include <hip/hip_runtime.h>

constexpr float EPS = 1e-5f;

// Buckets of 512 nodes: b = dst >> 9. For N <= 131072 we have B <= 256.
#define NPB_LOG 9
#define NPB 512

// ---------------- CSR build (locality-aware, 4 kernels) ----------------

__global__ void bucket_hist_kernel(const int* __restrict__ dst, int* __restrict__ bcnt,
                                   int E, int B) {
    __shared__ int h[256];
    int t = threadIdx.x;
    h[t] = 0;
    __syncthreads();
    for (int e = blockIdx.x * blockDim.x + t; e < E; e += gridDim.x * blockDim.x)
        atomicAdd(&h[dst[e] >> NPB_LOG], 1);
    __syncthreads();
    if (t < B && h[t]) atomicAdd(&bcnt[t], h[t]);
}

// single block: exclusive scan of B bucket counts -> bucket starts + partition cursors
__global__ void bucket_scan_kernel(const int* __restrict__ bcnt, int* __restrict__ bstart,
                                   int* __restrict__ cursorB, int B, int E) {
    __shared__ int tmp[256];
    int t = threadIdx.x;
    int v = (t < B) ? bcnt[t] : 0;
    tmp[t] = v;
    __syncthreads();
    for (int off = 1; off < 256; off <<= 1) {
        int x = tmp[t];
        if (t >= off) x += tmp[t - off];
        __syncthreads();
        tmp[t] = x;
        __syncthreads();
    }
    if (t < B) {
        int ex = tmp[t] - v;
        bstart[t] = ex;
        cursorB[t] = ex;
    }
    if (t == 0) bstart[B] = E;
}

// bin edges into bucket-contiguous storage; packed word = (src << 9) | (dst & 511)
__global__ __launch_bounds__(256) void partition_kernel(
    const int* __restrict__ src, const int* __restrict__ dst,
    int* __restrict__ cursorB, unsigned* __restrict__ ebuf, int E, int B) {
    __shared__ int hist[256];
    __shared__ int base[256];
    int t = threadIdx.x;
    hist[t] = 0;
    __syncthreads();
    int e0 = blockIdx.x * 4096;
    int e1 = min(e0 + 4096, E);
    for (int e = e0 + t; e < e1; e += 256)
        atomicAdd(&hist[dst[e] >> NPB_LOG], 1);
    __syncthreads();
    int h = hist[t];
    if (t < B && h) base[t] = atomicAdd(&cursorB[t], h);
    __syncthreads();
    hist[t] = 0;
    __syncthreads();
    for (int e = e0 + t; e < e1; e += 256) {
        int d = dst[e];
        int b = d >> NPB_LOG;
        int off = atomicAdd(&hist[b], 1);
        ebuf[base[b] + off] = ((unsigned)src[e] << NPB_LOG) | (unsigned)(d & (NPB - 1));
    }
}

// one block per bucket: node histogram + scan (rowptr, degInv), then scatter src into csr
__global__ __launch_bounds__(256) void build_csr_kernel(
    const unsigned* __restrict__ ebuf, const int* __restrict__ bstart,
    int* __restrict__ rowptr, float* __restrict__ degInv, int* __restrict__ csr,
    int N, int B) {
    __shared__ int cnt[NPB];
    __shared__ int cur[NPB];
    __shared__ int ps[256];
    int b = blockIdx.x;
    int t = threadIdx.x;
    int nbase = b << NPB_LOG;
    int nn = min(NPB, N - nbase);
    cnt[t] = 0;
    cnt[t + 256] = 0;
    __syncthreads();
    int ebeg = bstart[b], eend = bstart[b + 1];
    for (int e = ebeg + t; e < eend; e += 256)
        atomicAdd(&cnt[ebuf[e] & (NPB - 1)], 1);
    __syncthreads();
    int c0 = cnt[2 * t], c1 = cnt[2 * t + 1];
    int pair = c0 + c1;
    ps[t] = pair;
    __syncthreads();
    for (int off = 1; off < 256; off <<= 1) {
        int x = ps[t];
        if (t >= off) x += ps[t - off];
        __syncthreads();
        ps[t] = x;
        __syncthreads();
    }
    int exPair = ps[t] - pair;
    int g0 = ebeg + exPair;
    int g1 = g0 + c0;
    cur[2 * t] = g0;
    cur[2 * t + 1] = g1;
    if (2 * t < nn) {
        rowptr[nbase + 2 * t] = g0;
        degInv[nbase + 2 * t] = 1.0f / (float)max(c0, 1);
    }
    if (2 * t + 1 < nn) {
        rowptr[nbase + 2 * t + 1] = g1;
        degInv[nbase + 2 * t + 1] = 1.0f / (float)max(c1, 1);
    }
    if (b == B - 1 && t == 0) rowptr[N] = eend;
    __syncthreads();
    for (int e = ebeg + t; e < eend; e += 256) {
        unsigned p = ebuf[e];
        int pos = atomicAdd(&cur[p & (NPB - 1)], 1);
        csr[pos] = (int)(p >> NPB_LOG);
    }
}

// ---------------- mean aggregation over 128-wide rows ----------------
// 32 lanes per node, each lane owns one float4 column; edge loop unrolled x4.
__global__ void aggregate_kernel(const float* __restrict__ X, const int* __restrict__ rowptr,
                                 const int* __restrict__ csr_src, const float* __restrict__ degInv,
                                 float* __restrict__ agg, int n) {
    int idx = blockIdx.x * blockDim.x + threadIdx.x;
    int v = idx >> 5;
    int t = idx & 31;
    if (v >= n) return;
    int beg = rowptr[v], end = rowptr[v + 1];
    const float4* X4 = reinterpret_cast<const float4*>(X);
    float4 s0 = make_float4(0.f, 0.f, 0.f, 0.f);
    float4 s1 = make_float4(0.f, 0.f, 0.f, 0.f);
    int e = beg;
    for (; e + 4 <= end; e += 4) {
        int u0 = csr_src[e + 0];
        int u1 = csr_src[e + 1];
        int u2 = csr_src[e + 2];
        int u3 = csr_src[e + 3];
        float4 a = X4[(size_t)u0 * 32 + t];
        float4 b = X4[(size_t)u1 * 32 + t];
        float4 c = X4[(size_t)u2 * 32 + t];
        float4 d = X4[(size_t)u3 * 32 + t];
        s0.x += a.x + b.x; s0.y += a.y + b.y; s0.z += a.z + b.z; s0.w += a.w + b.w;
        s1.x += c.x + d.x; s1.y += c.y + d.y; s1.z += c.z + d.z; s1.w += c.w + d.w;
    }
    for (; e < end; ++e) {
        int u = csr_src[e];
        float4 a = X4[(size_t)u * 32 + t];
        s0.x += a.x; s0.y += a.y; s0.z += a.z; s0.w += a.w;
    }
    float di = degInv[v];
    float4 s;
    s.x = (s0.x + s1.x) * di;
    s.y = (s0.y + s1.y) * di;
    s.z = (s0.z + s1.z) * di;
    s.w = (s0.w + s1.w) * di;
    reinterpret_cast<float4*>(agg)[(size_t)v * 32 + t] = s;
}

// ---------------- fused dual-GEMM + bias + BN + ReLU (layers 0,1) ----------------
template <int DOUT, bool BNRELU>
__global__ __launch_bounds__(256) void fused_linear_kernel(
    const float* __restrict__ AGG, const float* __restrict__ X,
    const float* __restrict__ Wl, const float* __restrict__ bl,
    const float* __restrict__ Wr,
    const float* __restrict__ g, const float* __restrict__ bb,
    const float* __restrict__ mm, const float* __restrict__ vv,
    float* __restrict__ OUT, int n) {
    constexpr int TN = DOUT / 16;
    __shared__ float As[8][128];
    __shared__ float Ws[8][DOUT];

    int tid = threadIdx.x;
    int row0 = blockIdx.x * 128;
    int tx = tid & 15;
    int ty = tid >> 4;

    float acc[8][TN];
#pragma unroll
    for (int i = 0; i < 8; ++i)
#pragma unroll
        for (int j = 0; j < TN; ++j) acc[i][j] = 0.f;

    int arow = tid >> 1;
    int apart = tid & 1;

    for (int kt = 0; kt < 32; ++kt) {
        int kg = kt * 8;
        const float* Asrc = (kg < 128) ? AGG : X;
        int ka = (kg < 128) ? kg : (kg - 128);
        const float* Wsrc = (kg < 128) ? Wl : Wr;
        int kw = ka;

        float4 av = make_float4(0.f, 0.f, 0.f, 0.f);
        int r = row0 + arow;
        if (r < n)
            av = *reinterpret_cast<const float4*>(Asrc + (size_t)r * 128 + ka + apart * 4);

        float4 wv = make_float4(0.f, 0.f, 0.f, 0.f);
        int wr, wc;
        if (DOUT == 128) {
            wr = tid >> 5; wc = (tid & 31) * 4;
            wv = *reinterpret_cast<const float4*>(Wsrc + (size_t)(kw + wr) * DOUT + wc);
        } else {
            wr = tid >> 4; wc = (tid & 15) * 4;
            if (tid < 128)
                wv = *reinterpret_cast<const float4*>(Wsrc + (size_t)(kw + wr) * DOUT + wc);
        }

        __syncthreads();
        As[apart * 4 + 0][arow] = av.x;
        As[apart * 4 + 1][arow] = av.y;
        As[apart * 4 + 2][arow] = av.z;
        As[apart * 4 + 3][arow] = av.w;
        if (DOUT == 128 || tid < 128) {
            Ws[wr][wc + 0] = wv.x;
            Ws[wr][wc + 1] = wv.y;
            Ws[wr][wc + 2] = wv.z;
            Ws[wr][wc + 3] = wv.w;
        }
        __syncthreads();

#pragma unroll
        for (int kk = 0; kk < 8; ++kk) {
            float a[8], w[TN];
#pragma unroll
            for (int i = 0; i < 8; ++i) a[i] = As[kk][ty * 8 + i];
#pragma unroll
            for (int j = 0; j < TN; ++j) w[j] = Ws[kk][tx * TN + j];
#pragma unroll
            for (int i = 0; i < 8; ++i)
#pragma unroll
                for (int j = 0; j < TN; ++j) acc[i][j] += a[i] * w[j];
        }
    }

#pragma unroll
    for (int i = 0; i < 8; ++i) {
        int r = row0 + ty * 8 + i;
        if (r >= n) continue;
#pragma unroll
        for (int j = 0; j < TN; ++j) {
            int c = tx * TN + j;
            float h = acc[i][j] + bl[c];
            if (BNRELU) {
                h = g[c] * (h - mm[c]) * rsqrtf(vv[c] + EPS) + bb[c];
                h = fmaxf(h, 0.f);
            }
            OUT[(size_t)r * DOUT + c] = h;
        }
    }
}

// ---------------- layer 2: dual linear producing tmpL = H@Wl, tmpR = H@Wr + bl ----------------
__global__ __launch_bounds__(256) void dual_linear64_kernel(
    const float* __restrict__ H,
    const float* __restrict__ Wl, const float* __restrict__ bl,
    const float* __restrict__ Wr,
    float* __restrict__ tmpL, float* __restrict__ tmpR, int n) {
    __shared__ float As[8][128];
    __shared__ float WsL[8][64];
    __shared__ float WsR[8][64];

    int tid = threadIdx.x;
    int row0 = blockIdx.x * 128;
    int tx = tid & 15;
    int ty = tid >> 4;

    float accL[8][4], accR[8][4];
#pragma unroll
    for (int i = 0; i < 8; ++i)
#pragma unroll
        for (int j = 0; j < 4; ++j) { accL[i][j] = 0.f; accR[i][j] = 0.f; }

    int arow = tid >> 1;
    int apart = tid & 1;
    int wr = tid >> 5;
    int wc = (tid & 31) * 2;

    for (int kt = 0; kt < 16; ++kt) {
        int kg = kt * 8;

        float4 av = make_float4(0.f, 0.f, 0.f, 0.f);
        int r = row0 + arow;
        if (r < n)
            av = *reinterpret_cast<const float4*>(H + (size_t)r * 128 + kg + apart * 4);

        float2 wlv = *reinterpret_cast<const float2*>(Wl + (size_t)(kg + wr) * 64 + wc);
        float2 wrv = *reinterpret_cast<const float2*>(Wr + (size_t)(kg + wr) * 64 + wc);

        __syncthreads();
        As[apart * 4 + 0][arow] = av.x;
        As[apart * 4 + 1][arow] = av.y;
        As[apart * 4 + 2][arow] = av.z;
        As[apart * 4 + 3][arow] = av.w;
        WsL[wr][wc + 0] = wlv.x;
        WsL[wr][wc + 1] = wlv.y;
        WsR[wr][wc + 0] = wrv.x;
        WsR[wr][wc + 1] = wrv.y;
        __syncthreads();

#pragma unroll
        for (int kk = 0; kk < 8; ++kk) {
            float a[8], wl[4], wrg[4];
#pragma unroll
            for (int i = 0; i < 8; ++i) a[i] = As[kk][ty * 8 + i];
#pragma unroll
            for (int j = 0; j < 4; ++j) {
                wl[j]  = WsL[kk][tx * 4 + j];
                wrg[j] = WsR[kk][tx * 4 + j];
            }
#pragma unroll
            for (int i = 0; i < 8; ++i)
#pragma unroll
                for (int j = 0; j < 4; ++j) {
                    accL[i][j] += a[i] * wl[j];
                    accR[i][j] += a[i] * wrg[j];
                }
        }
    }

#pragma unroll
    for (int i = 0; i < 8; ++i) {
        int r = row0 + ty * 8 + i;
        if (r >= n) continue;
#pragma unroll
        for (int j = 0; j < 4; ++j) {
            int c = tx * 4 + j;
            tmpL[(size_t)r * 64 + c] = accL[i][j];
            tmpR[(size_t)r * 64 + c] = accR[i][j] + bl[c];
        }
    }
}

// ---------------- final: out = log_softmax( mean-agg(tmpL) + tmpR ) ----------------
__global__ void agg64_lsm_kernel(const float* __restrict__ tmpL, const float* __restrict__ tmpR,
                                 const int* __restrict__ rowptr, const int* __restrict__ csr_src,
                                 const float* __restrict__ degInv,
                                 float* __restrict__ out, int n) {
    int idx = blockIdx.x * blockDim.x + threadIdx.x;
    int v = idx >> 4;
    int t = idx & 15;
    if (v >= n) return;
    int beg = rowptr[v], end = rowptr[v + 1];
    const float4* L4 = reinterpret_cast<const float4*>(tmpL);
    float4 s0 = make_float4(0.f, 0.f, 0.f, 0.f);
    float4 s1 = make_float4(0.f, 0.f, 0.f, 0.f);
    int e = beg;
    for (; e + 4 <= end; e += 4) {
        int u0 = csr_src[e + 0];
        int u1 = csr_src[e + 1];
        int u2 = csr_src[e + 2];
        int u3 = csr_src[e + 3];
        float4 a = L4[(size_t)u0 * 16 + t];
        float4 b = L4[(size_t)u1 * 16 + t];
        float4 c = L4[(size_t)u2 * 16 + t];
        float4 d = L4[(size_t)u3 * 16 + t];
        s0.x += a.x + b.x; s0.y += a.y + b.y; s0.z += a.z + b.z; s0.w += a.w + b.w;
        s1.x += c.x + d.x; s1.y += c.y + d.y; s1.z += c.z + d.z; s1.w += c.w + d.w;
    }
    for (; e < end; ++e) {
        int u = csr_src[e];
        float4 a = L4[(size_t)u * 16 + t];
        s0.x += a.x; s0.y += a.y; s0.z += a.z; s0.w += a.w;
    }
    float di = degInv[v];
    float4 r4 = reinterpret_cast<const float4*>(tmpR)[(size_t)v * 16 + t];
    float y0 = (s0.x + s1.x) * di + r4.x;
    float y1 = (s0.y + s1.y) * di + r4.y;
    float y2 = (s0.z + s1.z) * di + r4.z;
    float y3 = (s0.w + s1.w) * di + r4.w;

    float mx = fmaxf(fmaxf(y0, y1), fmaxf(y2, y3));
#pragma unroll
    for (int o = 1; o < 16; o <<= 1) mx = fmaxf(mx, __shfl_xor(mx, o));
    float s = __expf(y0 - mx) + __expf(y1 - mx) + __expf(y2 - mx) + __expf(y3 - mx);
#pragma unroll
    for (int o = 1; o < 16; o <<= 1) s += __shfl_xor(s, o);
    float lse = mx + __logf(s);

    float4 o4;
    o4.x = y0 - lse; o4.y = y1 - lse; o4.z = y2 - lse; o4.w = y3 - lse;
    reinterpret_cast<float4*>(out)[(size_t)v * 16 + t] = o4;
}

// ---------------- launch ----------------

extern "C" void kernel_launch(void* const* d_in, const int* in_sizes, int n_in,
                              void* d_out, int out_size, void* d_ws, size_t ws_size,
                              hipStream_t stream) {
    const float* x   = (const float*)d_in[0];
    const int*   ei  = (const int*)d_in[1];
    const float* Wl0 = (const float*)d_in[2];
    const float* bl0 = (const float*)d_in[3];
    const float* Wr0 = (const float*)d_in[4];
    const float* g0  = (const float*)d_in[5];
    const float* b0  = (const float*)d_in[6];
    const float* m0  = (const float*)d_in[7];
    const float* v0  = (const float*)d_in[8];
    const float* Wl1 = (const float*)d_in[9];
    const float* bl1 = (const float*)d_in[10];
    const float* Wr1 = (const float*)d_in[11];
    const float* g1  = (const float*)d_in[12];
    const float* b1  = (const float*)d_in[13];
    const float* m1  = (const float*)d_in[14];
    const float* v1  = (const float*)d_in[15];
    const float* Wl2 = (const float*)d_in[16];
    const float* bl2 = (const float*)d_in[17];
    const float* Wr2 = (const float*)d_in[18];
    float* out = (float*)d_out;

    const int N = in_sizes[0] / 128;
    const int E = in_sizes[1] / 2;
    const int B = (N + NPB - 1) >> NPB_LOG;   // buckets (<= 256 for this problem)
    const int* src = ei;
    const int* dst = ei + E;

    char* ws = (char*)d_ws;
    size_t off = 0;
    auto alloc = [&](size_t bytes) -> void* {
        void* p = ws + off;
        off += (bytes + 255) & ~(size_t)255;
        return p;
    };
    int*   bcnt    = (int*)alloc(256 * 4);
    int*   bstart  = (int*)alloc(257 * 4);
    int*   cursorB = (int*)alloc(256 * 4);
    int*   rowptr  = (int*)alloc((size_t)(N + 1) * 4);
    float* degInv  = (float*)alloc((size_t)N * 4);
    int*   csr     = (int*)alloc((size_t)E * 4);
    float* agg     = (float*)alloc((size_t)N * 128 * 4);
    float* hA      = (float*)alloc((size_t)N * 128 * 4);
    float* hB      = (float*)alloc((size_t)N * 128 * 4);
    // aliases (lifetimes disjoint):
    unsigned* ebuf = (unsigned*)hA;            // used only during CSR build
    float* tmpL    = agg;                      // layer-2 temps overlay agg
    float* tmpR    = agg + (size_t)N * 64;

    hipMemsetAsync(bcnt, 0, 256 * 4, stream);

    bucket_hist_kernel<<<512, 256, 0, stream>>>(dst, bcnt, E, B);
    bucket_scan_kernel<<<1, 256, 0, stream>>>(bcnt, bstart, cursorB, B, E);
    partition_kernel<<<(E + 4095) / 4096, 256, 0, stream>>>(src, dst, cursorB, ebuf, E, B);
    build_csr_kernel<<<B, 256, 0, stream>>>(ebuf, bstart, rowptr, degInv, csr, N, B);

    int aggGrid = (int)(((size_t)N * 32 + 255) / 256);
    int gemmGrid = (N + 127) / 128;

    // layer 0
    aggregate_kernel<<<aggGrid, 256, 0, stream>>>(x, rowptr, csr, degInv, agg, N);
    fused_linear_kernel<128, true><<<gemmGrid, 256, 0, stream>>>(
        agg, x, Wl0, bl0, Wr0, g0, b0, m0, v0, hA, N);
    // layer 1
    aggregate_kernel<<<aggGrid, 256, 0, stream>>>(hA, rowptr, csr, degInv, agg, N);
    fused_linear_kernel<128, true><<<gemmGrid, 256, 0, stream>>>(
        agg, hA, Wl1, bl1, Wr1, g1, b1, m1, v1, hB, N);
    // layer 2: transform first (aggregation is linear), then 64-wide aggregate + fused log_softmax
    dual_linear64_kernel<<<gemmGrid, 256, 0, stream>>>(hB, Wl2, bl2, Wr2, tmpL, tmpR, N);
    agg64_lsm_kernel<<<(int)(((size_t)N * 16 + 255) / 256), 256, 0, stream>>>(
        tmpL, tmpR, rowptr, csr, degInv, out, N);
}

// Round 4
// 340.798 us; speedup vs baseline: 2.4767x; 1.8532x over previous
//
#include <hip/hip_runtime.h>

constexpr float EPS = 1e-5f;

#define NPB_LOG 9
#define NPB 512

typedef __attribute__((ext_vector_type(8))) __bf16 bf16x8;
typedef __attribute__((ext_vector_type(4))) float f32x4;

// ---------- bf16 helpers ----------
__device__ __forceinline__ float blo(unsigned u) { return __uint_as_float(u << 16); }
__device__ __forceinline__ float bhi(unsigned u) { return __uint_as_float(u & 0xffff0000u); }
__device__ __forceinline__ unsigned bf1(float f) {
    unsigned u = __float_as_uint(f);
    return (u + 0x7fffu + ((u >> 16) & 1u)) >> 16;
}
__device__ __forceinline__ unsigned pack2(float a, float b) { return bf1(a) | (bf1(b) << 16); }

// ---------------- CSR build (locality-aware) ----------------

__global__ void bucket_hist_kernel(const int* __restrict__ dst, int* __restrict__ bcnt,
                                   int E, int B) {
    __shared__ int h[256];
    int t = threadIdx.x;
    h[t] = 0;
    __syncthreads();
    for (int e = blockIdx.x * blockDim.x + t; e < E; e += gridDim.x * blockDim.x)
        atomicAdd(&h[dst[e] >> NPB_LOG], 1);
    __syncthreads();
    if (t < B && h[t]) atomicAdd(&bcnt[t], h[t]);
}

__global__ void bucket_scan_kernel(const int* __restrict__ bcnt, int* __restrict__ bstart,
                                   int* __restrict__ cursorB, int B, int E) {
    __shared__ int tmp[256];
    int t = threadIdx.x;
    int v = (t < B) ? bcnt[t] : 0;
    tmp[t] = v;
    __syncthreads();
    for (int off = 1; off < 256; off <<= 1) {
        int x = tmp[t];
        if (t >= off) x += tmp[t - off];
        __syncthreads();
        tmp[t] = x;
        __syncthreads();
    }
    if (t < B) {
        int ex = tmp[t] - v;
        bstart[t] = ex;
        cursorB[t] = ex;
    }
    if (t == 0) bstart[B] = E;
}

__global__ __launch_bounds__(256) void partition_kernel(
    const int* __restrict__ src, const int* __restrict__ dst,
    int* __restrict__ cursorB, unsigned* __restrict__ ebuf, int E, int B) {
    __shared__ int hist[256];
    __shared__ int base[256];
    int t = threadIdx.x;
    hist[t] = 0;
    __syncthreads();
    int e0 = blockIdx.x * 4096;
    int e1 = min(e0 + 4096, E);
    for (int e = e0 + t; e < e1; e += 256)
        atomicAdd(&hist[dst[e] >> NPB_LOG], 1);
    __syncthreads();
    int h = hist[t];
    if (t < B && h) base[t] = atomicAdd(&cursorB[t], h);
    __syncthreads();
    hist[t] = 0;
    __syncthreads();
    for (int e = e0 + t; e < e1; e += 256) {
        int d = dst[e];
        int b = d >> NPB_LOG;
        int off = atomicAdd(&hist[b], 1);
        ebuf[base[b] + off] = ((unsigned)src[e] << NPB_LOG) | (unsigned)(d & (NPB - 1));
    }
}

__global__ __launch_bounds__(256) void build_csr_kernel(
    const unsigned* __restrict__ ebuf, const int* __restrict__ bstart,
    int* __restrict__ rowptr, float* __restrict__ degInv, int* __restrict__ csr,
    int N, int B) {
    __shared__ int cnt[NPB];
    __shared__ int cur[NPB];
    __shared__ int ps[256];
    int b = blockIdx.x;
    int t = threadIdx.x;
    int nbase = b << NPB_LOG;
    int nn = min(NPB, N - nbase);
    cnt[t] = 0;
    cnt[t + 256] = 0;
    __syncthreads();
    int ebeg = bstart[b], eend = bstart[b + 1];
    for (int e = ebeg + t; e < eend; e += 256)
        atomicAdd(&cnt[ebuf[e] & (NPB - 1)], 1);
    __syncthreads();
    int c0 = cnt[2 * t], c1 = cnt[2 * t + 1];
    int pair = c0 + c1;
    ps[t] = pair;
    __syncthreads();
    for (int off = 1; off < 256; off <<= 1) {
        int x = ps[t];
        if (t >= off) x += ps[t - off];
        __syncthreads();
        ps[t] = x;
        __syncthreads();
    }
    int exPair = ps[t] - pair;
    int g0 = ebeg + exPair;
    int g1 = g0 + c0;
    cur[2 * t] = g0;
    cur[2 * t + 1] = g1;
    if (2 * t < nn) {
        rowptr[nbase + 2 * t] = g0;
        degInv[nbase + 2 * t] = 1.0f / (float)max(c0, 1);
    }
    if (2 * t + 1 < nn) {
        rowptr[nbase + 2 * t + 1] = g1;
        degInv[nbase + 2 * t + 1] = 1.0f / (float)max(c1, 1);
    }
    if (b == B - 1 && t == 0) rowptr[N] = eend;
    __syncthreads();
    for (int e = ebeg + t; e < eend; e += 256) {
        unsigned p = ebuf[e];
        int pos = atomicAdd(&cur[p & (NPB - 1)], 1);
        csr[pos] = (int)(p >> NPB_LOG);
    }
}

// ---------------- f32 -> bf16 conversion (4 elems/thread) ----------------
__global__ void cvt_bf16_kernel(const float* __restrict__ in, unsigned short* __restrict__ out,
                                int n4) {
    int i = blockIdx.x * blockDim.x + threadIdx.x;
    if (i < n4) {
        float4 v = reinterpret_cast<const float4*>(in)[i];
        uint2 o;
        o.x = pack2(v.x, v.y);
        o.y = pack2(v.z, v.w);
        reinterpret_cast<uint2*>(out)[i] = o;
    }
}

// ---------------- weight swizzle into MFMA fragment order ----------------
// out layout: [kt][ct][lane][8] bf16 ; k = kt*32 + (lane>>4)*8 + i ; col = ct*16 + (lane&15)
__global__ void swizzleW_kernel(const float* __restrict__ Wl, const float* __restrict__ Wr,
                                unsigned short* __restrict__ out,
                                int Khalf, int Ktotal, int DOUT) {
    int CT = DOUT >> 4;
    int total = (Ktotal >> 5) * CT * 64;
    int id = blockIdx.x * blockDim.x + threadIdx.x;
    if (id >= total) return;
    int lane = id & 63;
    int ctkt = id >> 6;
    int ct = ctkt % CT;
    int kt = ctkt / CT;
    int col = ct * 16 + (lane & 15);
    int k0 = kt * 32 + (lane >> 4) * 8;
#pragma unroll
    for (int i = 0; i < 8; ++i) {
        int k = k0 + i;
        float w = (k < Khalf) ? Wl[(size_t)k * DOUT + col] : Wr[(size_t)(k - Khalf) * DOUT + col];
        out[(size_t)id * 8 + i] = (unsigned short)bf1(w);
    }
}

// ---------------- fold BN into per-column affine: y = A*acc + B ----------------
__global__ void bnprep_kernel(const float* __restrict__ bl, const float* __restrict__ g,
                              const float* __restrict__ b, const float* __restrict__ m,
                              const float* __restrict__ v,
                              float* __restrict__ scaleA, float* __restrict__ biasB, int D) {
    int c = blockIdx.x * blockDim.x + threadIdx.x;
    if (c < D) {
        float A = g[c] * rsqrtf(v[c] + EPS);
        scaleA[c] = A;
        biasB[c] = (bl[c] - m[c]) * A + b[c];
    }
}

// ---------------- mean aggregation over 128-wide bf16 rows ----------------
// 32 lanes/node, 8 B (4 bf16) per lane; f32 accumulate; bf16 output.
__global__ void aggregate16_kernel(const unsigned short* __restrict__ X,
                                   const int* __restrict__ rowptr, const int* __restrict__ csr,
                                   const float* __restrict__ degInv,
                                   unsigned short* __restrict__ agg, int n) {
    int idx = blockIdx.x * blockDim.x + threadIdx.x;
    int v = idx >> 5;
    int t = idx & 31;
    if (v >= n) return;
    int beg = rowptr[v], end = rowptr[v + 1];
    const uint2* X2 = reinterpret_cast<const uint2*>(X);
    float s0 = 0.f, s1 = 0.f, s2 = 0.f, s3 = 0.f;
    int e = beg;
    for (; e + 4 <= end; e += 4) {
        int u0 = csr[e + 0], u1 = csr[e + 1], u2 = csr[e + 2], u3 = csr[e + 3];
        uint2 a = X2[(size_t)u0 * 32 + t];
        uint2 b = X2[(size_t)u1 * 32 + t];
        uint2 c = X2[(size_t)u2 * 32 + t];
        uint2 d = X2[(size_t)u3 * 32 + t];
        s0 += blo(a.x) + blo(b.x) + blo(c.x) + blo(d.x);
        s1 += bhi(a.x) + bhi(b.x) + bhi(c.x) + bhi(d.x);
        s2 += blo(a.y) + blo(b.y) + blo(c.y) + blo(d.y);
        s3 += bhi(a.y) + bhi(b.y) + bhi(c.y) + bhi(d.y);
    }
    for (; e < end; ++e) {
        int u = csr[e];
        uint2 a = X2[(size_t)u * 32 + t];
        s0 += blo(a.x); s1 += bhi(a.x); s2 += blo(a.y); s3 += bhi(a.y);
    }
    float di = degInv[v];
    uint2 o;
    o.x = pack2(s0 * di, s1 * di);
    o.y = pack2(s2 * di, s3 * di);
    reinterpret_cast<uint2*>(agg)[(size_t)v * 32 + t] = o;
}

// ---------------- MFMA dual-GEMM + affine-BN + ReLU, DOUT=128, K=256 ----------------
// block = 64 rows x 128 cols, 4 waves in 2x2; no LDS, B pre-swizzled.
__global__ __launch_bounds__(256) void gemm128_kernel(
    const unsigned short* __restrict__ A0, const unsigned short* __restrict__ A1,
    const unsigned short* __restrict__ Wsw,
    const float* __restrict__ scaleA, const float* __restrict__ biasB,
    unsigned short* __restrict__ OUT, int n) {
    int tid = threadIdx.x;
    int lane = tid & 63;
    int wave = tid >> 6;
    int wr = wave >> 1, wc = wave & 1;
    int row0 = blockIdx.x * 64 + wr * 32;
    int rlo = lane & 15, kq = lane >> 4;

    f32x4 acc[2][4];
#pragma unroll
    for (int rt = 0; rt < 2; ++rt)
#pragma unroll
        for (int c4 = 0; c4 < 4; ++c4)
#pragma unroll
            for (int k = 0; k < 4; ++k) acc[rt][c4][k] = 0.f;

    int r0 = row0 + rlo;
    int r1 = row0 + 16 + rlo;

    for (int kt = 0; kt < 8; ++kt) {
        const unsigned short* Aarr = (kt < 4) ? A0 : A1;
        int kb = (kt & 3) * 32 + kq * 8;
        bf16x8 a0, a1;
#pragma unroll
        for (int i = 0; i < 8; ++i) { a0[i] = (__bf16)0.f; a1[i] = (__bf16)0.f; }
        if (r0 < n) a0 = *reinterpret_cast<const bf16x8*>(Aarr + (size_t)r0 * 128 + kb);
        if (r1 < n) a1 = *reinterpret_cast<const bf16x8*>(Aarr + (size_t)r1 * 128 + kb);
#pragma unroll
        for (int c4 = 0; c4 < 4; ++c4) {
            int ct = wc * 4 + c4;
            bf16x8 b = *reinterpret_cast<const bf16x8*>(Wsw + ((size_t)(kt * 8 + ct) * 64 + lane) * 8);
            acc[0][c4] = __builtin_amdgcn_mfma_f32_16x16x32_bf16(a0, b, acc[0][c4], 0, 0, 0);
            acc[1][c4] = __builtin_amdgcn_mfma_f32_16x16x32_bf16(a1, b, acc[1][c4], 0, 0, 0);
        }
    }

#pragma unroll
    for (int rt = 0; rt < 2; ++rt)
#pragma unroll
        for (int c4 = 0; c4 < 4; ++c4) {
            int col = wc * 64 + c4 * 16 + rlo;
            float sA = scaleA[col];
            float sB = biasB[col];
#pragma unroll
            for (int i = 0; i < 4; ++i) {
                int r = row0 + rt * 16 + kq * 4 + i;
                if (r < n) {
                    float y = fmaxf(acc[rt][c4][i] * sA + sB, 0.f);
                    OUT[(size_t)r * 128 + col] = (unsigned short)bf1(y);
                }
            }
        }
}

// ---------------- layer 2: H@Wl2 -> tmpL (bf16), H@Wr2 + bl2 -> tmpR (f32) ----------------
__global__ __launch_bounds__(256) void dual64_kernel(
    const unsigned short* __restrict__ H,
    const unsigned short* __restrict__ WswL, const unsigned short* __restrict__ WswR,
    const float* __restrict__ bl,
    unsigned short* __restrict__ tmpL, float* __restrict__ tmpR, int n) {
    int tid = threadIdx.x;
    int lane = tid & 63;
    int wave = tid >> 6;
    int wr = wave >> 1, wc = wave & 1;
    int row0 = blockIdx.x * 64 + wr * 32;
    int rlo = lane & 15, kq = lane >> 4;

    f32x4 aL[2][2], aR[2][2];
#pragma unroll
    for (int rt = 0; rt < 2; ++rt)
#pragma unroll
        for (int c2 = 0; c2 < 2; ++c2)
#pragma unroll
            for (int k = 0; k < 4; ++k) { aL[rt][c2][k] = 0.f; aR[rt][c2][k] = 0.f; }

    int r0 = row0 + rlo;
    int r1 = row0 + 16 + rlo;

    for (int kt = 0; kt < 4; ++kt) {
        int kb = kt * 32 + kq * 8;
        bf16x8 a0, a1;
#pragma unroll
        for (int i = 0; i < 8; ++i) { a0[i] = (__bf16)0.f; a1[i] = (__bf16)0.f; }
        if (r0 < n) a0 = *reinterpret_cast<const bf16x8*>(H + (size_t)r0 * 128 + kb);
        if (r1 < n) a1 = *reinterpret_cast<const bf16x8*>(H + (size_t)r1 * 128 + kb);
#pragma unroll
        for (int c2 = 0; c2 < 2; ++c2) {
            int ct = wc * 2 + c2;
            bf16x8 bL = *reinterpret_cast<const bf16x8*>(WswL + ((size_t)(kt * 4 + ct) * 64 + lane) * 8);
            bf16x8 bR = *reinterpret_cast<const bf16x8*>(WswR + ((size_t)(kt * 4 + ct) * 64 + lane) * 8);
            aL[0][c2] = __builtin_amdgcn_mfma_f32_16x16x32_bf16(a0, bL, aL[0][c2], 0, 0, 0);
            aL[1][c2] = __builtin_amdgcn_mfma_f32_16x16x32_bf16(a1, bL, aL[1][c2], 0, 0, 0);
            aR[0][c2] = __builtin_amdgcn_mfma_f32_16x16x32_bf16(a0, bR, aR[0][c2], 0, 0, 0);
            aR[1][c2] = __builtin_amdgcn_mfma_f32_16x16x32_bf16(a1, bR, aR[1][c2], 0, 0, 0);
        }
    }

#pragma unroll
    for (int rt = 0; rt < 2; ++rt)
#pragma unroll
        for (int c2 = 0; c2 < 2; ++c2) {
            int col = wc * 32 + c2 * 16 + rlo;
            float bv = bl[col];
#pragma unroll
            for (int i = 0; i < 4; ++i) {
                int r = row0 + rt * 16 + kq * 4 + i;
                if (r < n) {
                    tmpL[(size_t)r * 64 + col] = (unsigned short)bf1(aL[rt][c2][i]);
                    tmpR[(size_t)r * 64 + col] = aR[rt][c2][i] + bv;
                }
            }
        }
}

// ---------------- final: out = log_softmax( mean-agg(tmpL) + tmpR ) ----------------
// 16 lanes/node, 8 B (4 bf16) per lane.
__global__ void agg64_lsm_kernel(const unsigned short* __restrict__ tmpL,
                                 const float* __restrict__ tmpR,
                                 const int* __restrict__ rowptr, const int* __restrict__ csr,
                                 const float* __restrict__ degInv,
                                 float* __restrict__ out, int n) {
    int idx = blockIdx.x * blockDim.x + threadIdx.x;
    int v = idx >> 4;
    int t = idx & 15;
    if (v >= n) return;
    int beg = rowptr[v], end = rowptr[v + 1];
    const uint2* L2p = reinterpret_cast<const uint2*>(tmpL);
    float s0 = 0.f, s1 = 0.f, s2 = 0.f, s3 = 0.f;
    int e = beg;
    for (; e + 4 <= end; e += 4) {
        int u0 = csr[e + 0], u1 = csr[e + 1], u2 = csr[e + 2], u3 = csr[e + 3];
        uint2 a = L2p[(size_t)u0 * 16 + t];
        uint2 b = L2p[(size_t)u1 * 16 + t];
        uint2 c = L2p[(size_t)u2 * 16 + t];
        uint2 d = L2p[(size_t)u3 * 16 + t];
        s0 += blo(a.x) + blo(b.x) + blo(c.x) + blo(d.x);
        s1 += bhi(a.x) + bhi(b.x) + bhi(c.x) + bhi(d.x);
        s2 += blo(a.y) + blo(b.y) + blo(c.y) + blo(d.y);
        s3 += bhi(a.y) + bhi(b.y) + bhi(c.y) + bhi(d.y);
    }
    for (; e < end; ++e) {
        int u = csr[e];
        uint2 a = L2p[(size_t)u * 16 + t];
        s0 += blo(a.x); s1 += bhi(a.x); s2 += blo(a.y); s3 += bhi(a.y);
    }
    float di = degInv[v];
    float4 r4 = reinterpret_cast<const float4*>(tmpR)[(size_t)v * 16 + t];
    float y0 = s0 * di + r4.x;
    float y1 = s1 * di + r4.y;
    float y2 = s2 * di + r4.z;
    float y3 = s3 * di + r4.w;

    float mx = fmaxf(fmaxf(y0, y1), fmaxf(y2, y3));
#pragma unroll
    for (int o = 1; o < 16; o <<= 1) mx = fmaxf(mx, __shfl_xor(mx, o));
    float s = __expf(y0 - mx) + __expf(y1 - mx) + __expf(y2 - mx) + __expf(y3 - mx);
#pragma unroll
    for (int o = 1; o < 16; o <<= 1) s += __shfl_xor(s, o);
    float lse = mx + __logf(s);

    float4 o4;
    o4.x = y0 - lse; o4.y = y1 - lse; o4.z = y2 - lse; o4.w = y3 - lse;
    reinterpret_cast<float4*>(out)[(size_t)v * 16 + t] = o4;
}

// ---------------- launch ----------------

extern "C" void kernel_launch(void* const* d_in, const int* in_sizes, int n_in,
                              void* d_out, int out_size, void* d_ws, size_t ws_size,
                              hipStream_t stream) {
    const float* x   = (const float*)d_in[0];
    const int*   ei  = (const int*)d_in[1];
    const float* Wl0 = (const float*)d_in[2];
    const float* bl0 = (const float*)d_in[3];
    const float* Wr0 = (const float*)d_in[4];
    const float* g0  = (const float*)d_in[5];
    const float* b0  = (const float*)d_in[6];
    const float* m0  = (const float*)d_in[7];
    const float* v0  = (const float*)d_in[8];
    const float* Wl1 = (const float*)d_in[9];
    const float* bl1 = (const float*)d_in[10];
    const float* Wr1 = (const float*)d_in[11];
    const float* g1  = (const float*)d_in[12];
    const float* b1  = (const float*)d_in[13];
    const float* m1  = (const float*)d_in[14];
    const float* v1  = (const float*)d_in[15];
    const float* Wl2 = (const float*)d_in[16];
    const float* bl2 = (const float*)d_in[17];
    const float* Wr2 = (const float*)d_in[18];
    float* out = (float*)d_out;

    const int N = in_sizes[0] / 128;
    const int E = in_sizes[1] / 2;
    const int B = (N + NPB - 1) >> NPB_LOG;
    const int* src = ei;
    const int* dst = ei + E;

    char* ws = (char*)d_ws;
    size_t off = 0;
    auto alloc = [&](size_t bytes) -> void* {
        void* p = ws + off;
        off += (bytes + 255) & ~(size_t)255;
        return p;
    };
    int*   bcnt    = (int*)alloc(256 * 4);
    int*   bstart  = (int*)alloc(257 * 4);
    int*   cursorB = (int*)alloc(256 * 4);
    int*   rowptr  = (int*)alloc((size_t)(N + 1) * 4);
    float* degInv  = (float*)alloc((size_t)N * 4);
    int*   csr     = (int*)alloc((size_t)E * 4);
    unsigned* ebuf = (unsigned*)alloc((size_t)E * 4);
    unsigned short* x16   = (unsigned short*)alloc((size_t)N * 128 * 2);
    unsigned short* agg16 = (unsigned short*)alloc((size_t)N * 128 * 2);
    unsigned short* hA16  = (unsigned short*)alloc((size_t)N * 128 * 2);
    unsigned short* hB16  = (unsigned short*)alloc((size_t)N * 128 * 2);
    unsigned short* tmpL  = (unsigned short*)alloc((size_t)N * 64 * 2);
    float* tmpR  = (float*)alloc((size_t)N * 64 * 4);
    unsigned short* Wsw0  = (unsigned short*)alloc(8 * 8 * 64 * 8 * 2);
    unsigned short* Wsw1  = (unsigned short*)alloc(8 * 8 * 64 * 8 * 2);
    unsigned short* WswL2 = (unsigned short*)alloc(4 * 4 * 64 * 8 * 2);
    unsigned short* WswR2 = (unsigned short*)alloc(4 * 4 * 64 * 8 * 2);
    float* bnA0 = (float*)alloc(128 * 4);
    float* bnB0 = (float*)alloc(128 * 4);
    float* bnA1 = (float*)alloc(128 * 4);
    float* bnB1 = (float*)alloc(128 * 4);

    hipMemsetAsync(bcnt, 0, 256 * 4, stream);

    // CSR build
    bucket_hist_kernel<<<512, 256, 0, stream>>>(dst, bcnt, E, B);
    bucket_scan_kernel<<<1, 256, 0, stream>>>(bcnt, bstart, cursorB, B, E);
    partition_kernel<<<(E + 4095) / 4096, 256, 0, stream>>>(src, dst, cursorB, ebuf, E, B);
    build_csr_kernel<<<B, 256, 0, stream>>>(ebuf, bstart, rowptr, degInv, csr, N, B);

    // prep: x -> bf16, weight swizzles, BN folds
    int n4 = N * 32;   // N*128/4
    cvt_bf16_kernel<<<(n4 + 255) / 256, 256, 0, stream>>>(x, x16, n4);
    swizzleW_kernel<<<16, 256, 0, stream>>>(Wl0, Wr0, Wsw0, 128, 256, 128);
    swizzleW_kernel<<<16, 256, 0, stream>>>(Wl1, Wr1, Wsw1, 128, 256, 128);
    swizzleW_kernel<<<4, 256, 0, stream>>>(Wl2, nullptr, WswL2, 128, 128, 64);
    swizzleW_kernel<<<4, 256, 0, stream>>>(Wr2, nullptr, WswR2, 128, 128, 64);
    bnprep_kernel<<<1, 128, 0, stream>>>(bl0, g0, b0, m0, v0, bnA0, bnB0, 128);
    bnprep_kernel<<<1, 128, 0, stream>>>(bl1, g1, b1, m1, v1, bnA1, bnB1, 128);

    int aggGrid = (int)(((size_t)N * 32 + 255) / 256);
    int gemmGrid = (N + 63) / 64;

    // layer 0
    aggregate16_kernel<<<aggGrid, 256, 0, stream>>>(x16, rowptr, csr, degInv, agg16, N);
    gemm128_kernel<<<gemmGrid, 256, 0, stream>>>(agg16, x16, Wsw0, bnA0, bnB0, hA16, N);
    // layer 1
    aggregate16_kernel<<<aggGrid, 256, 0, stream>>>(hA16, rowptr, csr, degInv, agg16, N);
    gemm128_kernel<<<gemmGrid, 256, 0, stream>>>(agg16, hA16, Wsw1, bnA1, bnB1, hB16, N);
    // layer 2: transform-then-aggregate + fused log_softmax
    dual64_kernel<<<gemmGrid, 256, 0, stream>>>(hB16, WswL2, WswR2, bl2, tmpL, tmpR, N);
    agg64_lsm_kernel<<<(int)(((size_t)N * 16 + 255) / 256), 256, 0, stream>>>(
        tmpL, tmpR, rowptr, csr, degInv, out, N);
}